// Round 11
// baseline (66.788 us; speedup 1.0000x reference)
//
#include <hip/hip_runtime.h>
#include <math.h>

#define NQ 14
#define NSTATE (1 << 14)
#define DEPTH  6
#define NT     1024             // 16 waves/block

typedef float v2f __attribute__((ext_vector_type(2)));

// dword-index swizzle: XOR bits 6,7,8 into 2,3,4 (GF(2)-linear)
__device__ __forceinline__ int swz(int n) { return n ^ ((n >> 4) & 28); }

// fused CNOT ladders (even after odd): m = sigma_e(sigma_o(n))
__device__ __forceinline__ int sigma(int n) {
    int m = n ^ ((n & 0x1554) >> 1);
    return m ^ ((m & 0x2AAA) >> 1);
}

// ---- VOP3P packed helpers; cs = (c, s) pair consumed via op_sel ----
// d = a * c  (src1 lo replicated)
__device__ __forceinline__ v2f pkmul_cc(v2f a, v2f cs) {
    v2f d;
    asm("v_pk_mul_f32 %0, %1, %2 op_sel:[0,0] op_sel_hi:[1,0]"
        : "=v"(d) : "v"(a), "v"(cs));
    return d;
}
// d = a * s  (src1 hi replicated)
__device__ __forceinline__ v2f pkmul_ss(v2f a, v2f cs) {
    v2f d;
    asm("v_pk_mul_f32 %0, %1, %2 op_sel:[0,1] op_sel_hi:[1,1]"
        : "=v"(d) : "v"(a), "v"(cs));
    return d;
}
// d = a * c + acc
__device__ __forceinline__ v2f pkfma_cc(v2f a, v2f cs, v2f acc) {
    v2f d;
    asm("v_pk_fma_f32 %0, %1, %2, %3 op_sel:[0,0,0] op_sel_hi:[1,0,1]"
        : "=v"(d) : "v"(a), "v"(cs), "v"(acc));
    return d;
}
// d = -(a * s) + acc
__device__ __forceinline__ v2f pkfma_nss(v2f a, v2f cs, v2f acc) {
    v2f d;
    asm("v_pk_fma_f32 %0, %1, %2, %3 op_sel:[0,1,0] op_sel_hi:[1,1,1] neg_lo:[0,1,0] neg_hi:[0,1,0]"
        : "=v"(d) : "v"(a), "v"(cs), "v"(acc));
    return d;
}
// intra-pair rotate: d.lo = -s*a.hi + acc.lo ; d.hi = s*a.lo + acc.hi
__device__ __forceinline__ v2f pkfma_sw(v2f a, v2f cs, v2f acc) {
    v2f d;
    asm("v_pk_fma_f32 %0, %1, %2, %3 op_sel:[1,1,0] op_sel_hi:[0,1,1] neg_lo:[0,1,0] neg_hi:[0,0,0]"
        : "=v"(d) : "v"(a), "v"(cs), "v"(acc));
    return d;
}
// d = a * sg + acc  (sg both halves)
__device__ __forceinline__ v2f pkfma(v2f a, v2f b, v2f acc) {
    v2f d;
    asm("v_pk_fma_f32 %0, %1, %2, %3"
        : "=v"(d) : "v"(a), "v"(b), "v"(acc));
    return d;
}

// wire on the packing bit (intra-float2): 2 pk-instr per float2
__device__ __forceinline__ void ry_pk0(v2f (&p)[8], v2f cs) {
#pragma unroll
    for (int j = 0; j < 8; ++j)
        p[j] = pkfma_sw(p[j], cs, pkmul_cc(p[j], cs));
}
// wire on pair-index bit JB (0..2): 4 pk-instr per float2-pair
template <int JB>
__device__ __forceinline__ void ry_pkN(v2f (&p)[8], v2f cs) {
#pragma unroll
    for (int j = 0; j < 8; ++j) {
        if (!((j >> JB) & 1)) {
            const int j1 = j | (1 << JB);
            v2f a0 = p[j], a1 = p[j1];
            p[j]  = pkfma_nss(a1, cs, pkmul_cc(a0, cs));
            p[j1] = pkfma_cc(a1, cs, pkmul_ss(a0, cs));
        }
    }
}
// wire on lane bit via DPP quad_perm (0xB1 = lane^1, 0x4E = lane^2)
template <int CTRL>
__device__ __forceinline__ void ry_pkdpp(v2f (&p)[8], v2f cs, float sg) {
    v2f sgv; sgv.x = sg; sgv.y = sg;
#pragma unroll
    for (int j = 0; j < 8; ++j) {
        v2f pt;
        pt.x = __int_as_float(__builtin_amdgcn_update_dpp(
            0, __float_as_int(p[j].x), CTRL, 0xF, 0xF, true));
        pt.y = __int_as_float(__builtin_amdgcn_update_dpp(
            0, __float_as_int(p[j].y), CTRL, 0xF, 0xF, true));
        p[j] = pkfma(pt, sgv, pkmul_cc(p[j], cs));
    }
}

__global__ __launch_bounds__(NT, 4)
void vqc_kernel(const float* __restrict__ X,    // (512,14)
                const float* __restrict__ TH,   // (6,14)
                const float* __restrict__ A,    // (14,28)
                const float* __restrict__ Bc,   // (14,28)  unused: state stays real
                const float* __restrict__ D,    // (14,8)
                float* __restrict__ out)        // (512,2)
{
    __shared__ __align__(16) float st[NSTATE];  // 64 KiB real state
    __shared__ float2 tb[DEPTH * NQ];           // (cos,sin) per theta
    __shared__ float2 xf[NQ];                   // (c-s, c+s) per amplitude bit j
    __shared__ float  red[2 * (NT / 64)];

    const int t = threadIdx.x;
    const int b = blockIdx.x;

    // ---- trig tables (uniform work once per block) ----
    if (t < DEPTH * NQ) {
        float s, c;
        __sincosf(0.5f * TH[t], &s, &c);
        tb[t] = make_float2(c, s);
    } else if (t < DEPTH * NQ + NQ) {
        const int j = t - DEPTH * NQ;           // amplitude-bit j <-> wire 13-j
        float s, c;
        __sincosf(0.5f * X[b * NQ + (13 - j)], &s, &c);
        xf[j] = make_float2(c - s, c + s);
    }
    __syncthreads();

    // ---- layer 0 P1: product state at sigma(n), rotate wires 13..10 (amp 0-3) ----
    {
        const int mt = sigma(t << 4);
        float sh = 1.0f / 128.0f;
#pragma unroll
        for (int j = 4; j < 14; ++j) {
            float2 f = xf[j];
            sh *= ((mt >> j) & 1) ? f.y : f.x;
        }
        float fa[4], fb[4];
#pragma unroll
        for (int j = 0; j < 4; ++j) {
            float2 f = xf[j];
            const int mj = (mt >> j) & 1;
            fa[j] = mj ? f.y : f.x;
            fb[j] = mj ? f.x : f.y;
        }
        float pp[16];
#pragma unroll
        for (int i = 0; i < 16; ++i) {
            const int sl = sigma(i);
            float v = sh;
            v *= (sl & 1)        ? fb[0] : fa[0];
            v *= ((sl >> 1) & 1) ? fb[1] : fa[1];
            v *= ((sl >> 2) & 1) ? fb[2] : fa[2];
            v *= ((sl >> 3) & 1) ? fb[3] : fa[3];
            pp[i] = v;
        }
        v2f p[8];
#pragma unroll
        for (int j = 0; j < 8; ++j) { p[j].x = pp[2 * j]; p[j].y = pp[2 * j + 1]; }
        v2f c13, c12, c11, c10;
        { float2 q = tb[13]; c13.x = q.x; c13.y = q.y; }
        { float2 q = tb[12]; c12.x = q.x; c12.y = q.y; }
        { float2 q = tb[11]; c11.x = q.x; c11.y = q.y; }
        { float2 q = tb[10]; c10.x = q.x; c10.y = q.y; }
        ry_pk0(p, c13);                          // amp0 <-> wire 13 (pack bit)
        ry_pkN<0>(p, c12);                       // amp1
        ry_pkN<1>(p, c11);                       // amp2
        ry_pkN<2>(p, c10);                       // amp3
        const int wb = swz(t << 4);
#pragma unroll
        for (int g = 0; g < 4; ++g)
            *(float4*)&st[wb ^ (g << 2)] =
                make_float4(p[2 * g].x, p[2 * g].y, p[2 * g + 1].x, p[2 * g + 1].y);
    }
    __syncthreads();

    // ---- layers: P1 (CNOT + 13-10), P2 (9-6 reg + 5,4 DPP), P3 (3-0) ----
    for (int k = 0; k < DEPTH; ++k) {
        const float2* tbk = tb + k * NQ;

        if (k > 0) {
            // P1: gather through sigma (b128), rotate amp 0-3 (pack bit = amp0)
            const int rb = swz(sigma(t << 4) & ~15);
            float tmpf[16];
#pragma unroll
            for (int g = 0; g < 4; ++g)
                *(float4*)&tmpf[g * 4] = *(const float4*)&st[rb ^ (g << 2)];
            const int t0 = t & 1;
            v2f p[8];
#pragma unroll
            for (int j = 0; j < 8; ++j) {
                const int j0 = j & 1, j1 = (j >> 1) & 1, j2 = (j >> 2) & 1;
                const int sx = (j0 ^ j1) | ((j0 ^ j1) << 1) | ((j1 ^ j2) << 2) | (j2 << 3);
                const int sy = sx ^ 1;
                p[j].x = t0 ? tmpf[sx ^ 12] : tmpf[sx];
                p[j].y = t0 ? tmpf[sy ^ 12] : tmpf[sy];
            }
            __syncthreads();                     // all gather-reads before any write
            v2f c13, c12, c11, c10;
            { float2 q = tbk[13]; c13.x = q.x; c13.y = q.y; }
            { float2 q = tbk[12]; c12.x = q.x; c12.y = q.y; }
            { float2 q = tbk[11]; c11.x = q.x; c11.y = q.y; }
            { float2 q = tbk[10]; c10.x = q.x; c10.y = q.y; }
            ry_pk0(p, c13);
            ry_pkN<0>(p, c12);
            ry_pkN<1>(p, c11);
            ry_pkN<2>(p, c10);
            const int wb = swz(t << 4);
#pragma unroll
            for (int g = 0; g < 4; ++g)
                *(float4*)&st[wb ^ (g << 2)] =
                    make_float4(p[2 * g].x, p[2 * g].y, p[2 * g + 1].x, p[2 * g + 1].y);
            __syncthreads();
        }

        // P2: in-place RMW. pack bit = amp5 (+32 dwords); j bits = amp4,6,7.
        // Rotates wires 9-6 (reg) + wires 5,4 (DPP lane bits 0,1).
        {
            const int raw = ((t >> 2) & 15) | ((t & 1) << 8) | ((t & 2) << 8)
                          | (((t >> 6) & 15) << 10);
            const int base2 = swz(raw);
            v2f p[8];
#pragma unroll
            for (int j = 0; j < 8; ++j) {
                const int ip = (j & 1) | ((j & 6) << 1);       // amp4 | amp6,7
                const int vx = base2 ^ (ip << 4) ^ (ip & 12);  // swz(ip<<4) folded
                p[j].x = st[vx];
                p[j].y = st[vx + 32];
            }
            v2f c9, c8, c7, c6;
            { float2 q = tbk[9]; c9.x = q.x; c9.y = q.y; }
            { float2 q = tbk[8]; c8.x = q.x; c8.y = q.y; }
            { float2 q = tbk[7]; c7.x = q.x; c7.y = q.y; }
            { float2 q = tbk[6]; c6.x = q.x; c6.y = q.y; }
            ry_pk0(p, c8);                       // amp5 (pack bit) <-> wire 8
            ry_pkN<0>(p, c9);                    // amp4 <-> wire 9
            ry_pkN<1>(p, c7);                    // amp6 <-> wire 7
            ry_pkN<2>(p, c6);                    // amp7 <-> wire 6
            {
                float2 w5 = tbk[5], w4 = tbk[4];
                v2f c5, c4;
                c5.x = w5.x; c5.y = w5.y;
                c4.x = w4.x; c4.y = w4.y;
                const float sg5 = (t & 1) ? w5.y : -w5.y;   // amp8 = lane bit 0
                const float sg4 = (t & 2) ? w4.y : -w4.y;   // amp9 = lane bit 1
                ry_pkdpp<0xB1>(p, c5, sg5);
                ry_pkdpp<0x4E>(p, c4, sg4);
            }
#pragma unroll
            for (int j = 0; j < 8; ++j) {
                const int ip = (j & 1) | ((j & 6) << 1);
                const int vx = base2 ^ (ip << 4) ^ (ip & 12);
                st[vx]      = p[j].x;
                st[vx + 32] = p[j].y;
            }
            __syncthreads();
        }

        // P3: in-place RMW. pack bit = amp10 (+1024); j bits = amp11,12,13.
        {
            const int base3 = swz(t);
            v2f p[8];
#pragma unroll
            for (int j = 0; j < 8; ++j) {
                p[j].x = st[base3 + (j << 11)];
                p[j].y = st[base3 + (j << 11) + 1024];
            }
            v2f c3, c2, c1, c0;
            { float2 q = tbk[3]; c3.x = q.x; c3.y = q.y; }
            { float2 q = tbk[2]; c2.x = q.x; c2.y = q.y; }
            { float2 q = tbk[1]; c1.x = q.x; c1.y = q.y; }
            { float2 q = tbk[0]; c0.x = q.x; c0.y = q.y; }
            ry_pk0(p, c3);                       // amp10 (pack bit) <-> wire 3
            ry_pkN<0>(p, c2);                    // amp11 <-> wire 2
            ry_pkN<1>(p, c1);                    // amp12 <-> wire 1
            ry_pkN<2>(p, c0);                    // amp13 <-> wire 0
#pragma unroll
            for (int j = 0; j < 8; ++j) {
                st[base3 + (j << 11)]        = p[j].x;
                st[base3 + (j << 11) + 1024] = p[j].y;
            }
            __syncthreads();
        }
    }

    // ---- expectations (real state: B drops out) ----
    float e[2];
#pragma unroll
    for (int q = 0; q < 2; ++q) {
        const int shift = 11 - q;
        float dg[8];
#pragma unroll
        for (int i = 0; i < 7; ++i) dg[i] = 2.0f * D[q * 8 + i + 1];
        dg[7] = 0.0f;
        float acc = 0.0f;
        const int lowmask = (1 << shift) - 1;
        for (int r = t; r < NSTATE / 8; r += NT) {   // 2 iterations
            const int base = ((r >> shift) << (shift + 3)) | (r & lowmask);
            float ps[8];
#pragma unroll
            for (int i = 0; i < 8; ++i) ps[i] = st[swz(base + (i << shift))];
#pragma unroll
            for (int i = 0; i < 8; ++i) acc += dg[i] * ps[i] * ps[i];
            int kk = 0;
#pragma unroll
            for (int i = 1; i < 8; ++i)
#pragma unroll
                for (int j = 0; j < i; ++j, ++kk)
                    acc += 2.0f * A[q * 28 + kk] * ps[i] * ps[j];
        }
        e[q] = acc;
    }

    // ---- block reduction ----
    float v0 = e[0], v1 = e[1];
#pragma unroll
    for (int o = 32; o > 0; o >>= 1) {
        v0 += __shfl_down(v0, o);
        v1 += __shfl_down(v1, o);
    }
    if ((t & 63) == 0) {
        red[(t >> 6) * 2]     = v0;
        red[(t >> 6) * 2 + 1] = v1;
    }
    __syncthreads();
    if (t == 0) {
        float s0 = 0.0f, s1 = 0.0f;
#pragma unroll
        for (int i = 0; i < NT / 64; ++i) { s0 += red[i * 2]; s1 += red[i * 2 + 1]; }
        out[b * 2 + 0] = s0;
        out[b * 2 + 1] = s1;
    }
}

extern "C" void kernel_launch(void* const* d_in, const int* in_sizes, int n_in,
                              void* d_out, int out_size, void* d_ws, size_t ws_size,
                              hipStream_t stream) {
    const float* X  = (const float*)d_in[0];
    const float* TH = (const float*)d_in[1];
    const float* A  = (const float*)d_in[2];
    const float* Bc = (const float*)d_in[3];
    const float* D  = (const float*)d_in[4];
    float* out = (float*)d_out;
    vqc_kernel<<<512, NT, 0, stream>>>(X, TH, A, Bc, D, out);
}

// Round 12
// 54.415 us; speedup vs baseline: 1.2274x; 1.2274x over previous
//
#include <hip/hip_runtime.h>
#include <math.h>

#define NQ 14
#define NSTATE (1 << 14)
#define DEPTH  6
#define NT     1024             // 16 waves/block

// dword-index swizzle: XOR bits 6,7,8 into 2,3,4 (GF(2)-linear)
__device__ __forceinline__ int swz(int n) { return n ^ ((n >> 4) & 28); }

// fused CNOT ladders (even after odd): m = sigma_e(sigma_o(n))
__device__ __forceinline__ int sigma(int n) {
    int m = n ^ ((n & 0x1554) >> 1);
    return m ^ ((m & 0x2AAA) >> 1);
}

// RY on p-index bit JB over a 16-amp real register block
template <int JB>
__device__ __forceinline__ void ry16(float (&p)[16], float c, float s) {
#pragma unroll
    for (int i = 0; i < 16; ++i) {
        if (!((i >> JB) & 1)) {
            const int i1 = i | (1 << JB);
            float a0 = p[i], a1 = p[i1];
            p[i]  = c * a0 - s * a1;
            p[i1] = s * a0 + c * a1;
        }
    }
}

// RY across lane bit 0/1 via DPP quad_perm (VALU pipe, verified r9/r10).
// CTRL: 0xB1 = xor lane^1, 0x4E = xor lane^2.  sg = (lane bit set)? +s : -s
template <int CTRL>
__device__ __forceinline__ void ry_dpp(float (&p)[16], float c, float sg) {
#pragma unroll
    for (int i = 0; i < 16; ++i) {
        float partner = __int_as_float(__builtin_amdgcn_update_dpp(
            0, __float_as_int(p[i]), CTRL, 0xF, 0xF, true));
        p[i] = c * p[i] + sg * partner;
    }
}

// quadratic form over one 8-amp observable group (real state: B drops out)
__device__ __forceinline__ float quad8(const float (&ps)[8],
                                       const float* __restrict__ A,
                                       const float* __restrict__ D, int q) {
    float acc = 0.0f;
#pragma unroll
    for (int i = 0; i < 7; ++i) acc += 2.0f * D[q * 8 + i + 1] * ps[i] * ps[i];
    int kk = 0;
#pragma unroll
    for (int i = 1; i < 8; ++i)
#pragma unroll
        for (int j = 0; j < i; ++j, ++kk)
            acc += 2.0f * A[q * 28 + kk] * ps[i] * ps[j];
    return acc;
}

__global__ __launch_bounds__(NT, 4)
void vqc_kernel(const float* __restrict__ X,    // (512,14)
                const float* __restrict__ TH,   // (6,14)
                const float* __restrict__ A,    // (14,28)
                const float* __restrict__ Bc,   // (14,28)  unused: state stays real
                const float* __restrict__ D,    // (14,8)
                float* __restrict__ out)        // (512,2)
{
    __shared__ __align__(16) float st[NSTATE];  // 64 KiB real state
    __shared__ float2 tb[DEPTH * NQ];           // (cos,sin) per theta
    __shared__ float2 xf[NQ];                   // (c-s, c+s) per amplitude bit j
    __shared__ float  red[2 * (NT / 64)];

    const int t = threadIdx.x;
    const int b = blockIdx.x;

    // ---- trig tables (uniform work once per block) ----
    if (t < DEPTH * NQ) {
        float s, c;
        __sincosf(0.5f * TH[t], &s, &c);
        tb[t] = make_float2(c, s);
    } else if (t < DEPTH * NQ + NQ) {
        const int j = t - DEPTH * NQ;           // amplitude-bit j <-> wire 13-j
        float s, c;
        __sincosf(0.5f * X[b * NQ + (13 - j)], &s, &c);
        xf[j] = make_float2(c - s, c + s);
    }
    __syncthreads();

    // ---- layer 0 P1: product state at sigma(n), rotate wires 13..10 (amp 0-3) ----
    {
        const int mt = sigma(t << 4);
        float sh = 1.0f / 128.0f;
#pragma unroll
        for (int j = 4; j < 14; ++j) {
            float2 f = xf[j];
            sh *= ((mt >> j) & 1) ? f.y : f.x;
        }
        float fa[4], fb[4];
#pragma unroll
        for (int j = 0; j < 4; ++j) {
            float2 f = xf[j];
            const int mj = (mt >> j) & 1;
            fa[j] = mj ? f.y : f.x;
            fb[j] = mj ? f.x : f.y;
        }
        float p[16];
#pragma unroll
        for (int i = 0; i < 16; ++i) {
            const int sl = sigma(i);
            float v = sh;
            v *= (sl & 1)        ? fb[0] : fa[0];
            v *= ((sl >> 1) & 1) ? fb[1] : fa[1];
            v *= ((sl >> 2) & 1) ? fb[2] : fa[2];
            v *= ((sl >> 3) & 1) ? fb[3] : fa[3];
            p[i] = v;
        }
        float2 q0 = tb[13], q1 = tb[12], q2 = tb[11], q3 = tb[10];
        ry16<0>(p, q0.x, q0.y);
        ry16<1>(p, q1.x, q1.y);
        ry16<2>(p, q2.x, q2.y);
        ry16<3>(p, q3.x, q3.y);
        const int wb = swz(t << 4);
#pragma unroll
        for (int g = 0; g < 4; ++g)
            *(float4*)&st[wb ^ (g << 2)] =
                make_float4(p[4 * g], p[4 * g + 1], p[4 * g + 2], p[4 * g + 3]);
    }
    __syncthreads();

    // ---- layers: P1 (CNOT + 13-10), P2 (9-6 reg + 5,4 DPP), P3 (3-0) ----
    for (int k = 0; k < DEPTH; ++k) {
        const float2* tbk = tb + k * NQ;

        if (k > 0) {
            // P1: gather through sigma (b128). The in-block permute's lane-
            // dependent XOR 12 (t0 = n bit 4) flips only the float4-group
            // bits, so it folds into the read address; the remaining
            // permutation is compile-time register renaming.
            const int rb = swz(sigma(t << 4) & ~15) ^ ((t & 1) * 12);
            float tmpf[16];
#pragma unroll
            for (int g = 0; g < 4; ++g)
                *(float4*)&tmpf[g * 4] = *(const float4*)&st[rb ^ (g << 2)];
            float p[16];
#pragma unroll
            for (int i = 0; i < 16; ++i) {
                const int i0 = i & 1, i1 = (i >> 1) & 1, i2 = (i >> 2) & 1, i3 = (i >> 3) & 1;
                const int s = (i0 ^ i1 ^ i2) | ((i1 ^ i2) << 1) | ((i2 ^ i3) << 2) | (i3 << 3);
                p[i] = tmpf[s];                  // compile-time shuffle
            }
            __syncthreads();                     // all gather-reads before any write
            float2 q0 = tbk[13], q1 = tbk[12], q2 = tbk[11], q3 = tbk[10];
            ry16<0>(p, q0.x, q0.y);
            ry16<1>(p, q1.x, q1.y);
            ry16<2>(p, q2.x, q2.y);
            ry16<3>(p, q3.x, q3.y);
            const int wb = swz(t << 4);
#pragma unroll
            for (int g = 0; g < 4; ++g)
                *(float4*)&st[wb ^ (g << 2)] =
                    make_float4(p[4 * g], p[4 * g + 1], p[4 * g + 2], p[4 * g + 3]);
            __syncthreads();
        }

        // P2: in-place RMW. regs = amp 4-7 (wires 9-6); DPP lanes t0,t1 = amp 8,9
        // (wires 5,4). Pairs over amp bit 5 -> additive +32 dwords (ds_read2).
        {
            const int raw = ((t >> 2) & 15) | ((t & 1) << 8) | ((t & 2) << 8)
                          | (((t >> 6) & 15) << 10);
            const int base2 = swz(raw);
            float p[16];
#pragma unroll
            for (int ip = 0; ip < 16; ++ip) {
                if ((ip & 2) == 0) {
                    const int v = base2 ^ (ip << 4) ^ (ip & 12);   // swz(ip<<4) folded
                    p[ip]     = st[v];
                    p[ip | 2] = st[v + 32];
                }
            }
            float2 q0 = tbk[9], q1 = tbk[8], q2 = tbk[7], q3 = tbk[6];
            ry16<0>(p, q0.x, q0.y);             // amp4 <-> wire 9
            ry16<1>(p, q1.x, q1.y);             // amp5 <-> wire 8
            ry16<2>(p, q2.x, q2.y);             // amp6 <-> wire 7
            ry16<3>(p, q3.x, q3.y);             // amp7 <-> wire 6
            float2 w5 = tbk[5], w4 = tbk[4];
            const float sg5 = (t & 1) ? w5.y : -w5.y;   // amp8 = lane bit 0
            const float sg4 = (t & 2) ? w4.y : -w4.y;   // amp9 = lane bit 1
            ry_dpp<0xB1>(p, w5.x, sg5);
            ry_dpp<0x4E>(p, w4.x, sg4);
#pragma unroll
            for (int ip = 0; ip < 16; ++ip) {
                if ((ip & 2) == 0) {
                    const int v = base2 ^ (ip << 4) ^ (ip & 12);
                    st[v]      = p[ip];
                    st[v + 32] = p[ip | 2];
                }
            }
            __syncthreads();
        }

        // P3: regs = amp 10-13 (wires 3-0). Purely additive addresses
        // (base + i*1024 dwords; swz untouched). Last layer: no store —
        // expectations are computed directly from the register block.
        {
            const int base3 = swz(t);
            float p[16];
#pragma unroll
            for (int i = 0; i < 16; ++i) p[i] = st[base3 + (i << 10)];
            float2 q0 = tbk[3], q1 = tbk[2], q2 = tbk[1], q3 = tbk[0];
            ry16<0>(p, q0.x, q0.y);             // amp10 <-> wire 3
            ry16<1>(p, q1.x, q1.y);             // amp11 <-> wire 2
            ry16<2>(p, q2.x, q2.y);             // amp12 <-> wire 1
            ry16<3>(p, q3.x, q3.y);             // amp13 <-> wire 0
            if (k < DEPTH - 1) {
#pragma unroll
                for (int i = 0; i < 16; ++i) st[base3 + (i << 10)] = p[i];
                __syncthreads();
            } else {
                // ---- fused expectations from the P3 register block ----
                // q=0: observable bits amp11,12,13 (i bit0=amp11); groups a=amp10
                // q=1: observable bits amp10,11,12 (i bit0=amp10); groups b=amp13
                float e0 = 0.0f, e1 = 0.0f;
#pragma unroll
                for (int a = 0; a < 2; ++a) {
                    float ps[8];
#pragma unroll
                    for (int i = 0; i < 8; ++i) ps[i] = p[(i << 1) | a];
                    e0 += quad8(ps, A, D, 0);
                }
#pragma unroll
                for (int bb = 0; bb < 2; ++bb) {
                    float ps[8];
#pragma unroll
                    for (int i = 0; i < 8; ++i) ps[i] = p[i | (bb << 3)];
                    e1 += quad8(ps, A, D, 1);
                }
                // ---- block reduction ----
#pragma unroll
                for (int o = 32; o > 0; o >>= 1) {
                    e0 += __shfl_down(e0, o);
                    e1 += __shfl_down(e1, o);
                }
                if ((t & 63) == 0) {
                    red[(t >> 6) * 2]     = e0;
                    red[(t >> 6) * 2 + 1] = e1;
                }
                __syncthreads();
                if (t == 0) {
                    float s0 = 0.0f, s1 = 0.0f;
#pragma unroll
                    for (int i = 0; i < NT / 64; ++i) {
                        s0 += red[i * 2];
                        s1 += red[i * 2 + 1];
                    }
                    out[b * 2 + 0] = s0;
                    out[b * 2 + 1] = s1;
                }
            }
        }
    }
}

extern "C" void kernel_launch(void* const* d_in, const int* in_sizes, int n_in,
                              void* d_out, int out_size, void* d_ws, size_t ws_size,
                              hipStream_t stream) {
    const float* X  = (const float*)d_in[0];
    const float* TH = (const float*)d_in[1];
    const float* A  = (const float*)d_in[2];
    const float* Bc = (const float*)d_in[3];
    const float* D  = (const float*)d_in[4];
    float* out = (float*)d_out;
    vqc_kernel<<<512, NT, 0, stream>>>(X, TH, A, Bc, D, out);
}

// Round 13
// 47.840 us; speedup vs baseline: 1.3961x; 1.1374x over previous
//
#include <hip/hip_runtime.h>
#include <math.h>

#define NQ 14
#define NSTATE (1 << 14)
#define DEPTH  6
#define NT     1024             // 16 waves/block

// dword-index swizzle: XOR bits 6,7,8 into 2,3,4 (GF(2)-linear)
__device__ __forceinline__ int swz(int n) { return n ^ ((n >> 4) & 28); }

// fused CNOT ladders (even after odd): m = sigma_e(sigma_o(n))
__device__ __forceinline__ int sigma(int n) {
    int m = n ^ ((n & 0x1554) >> 1);
    return m ^ ((m & 0x2AAA) >> 1);
}

// RY on p-index bit JB over a 16-amp real register block
template <int JB>
__device__ __forceinline__ void ry16(float (&p)[16], float c, float s) {
#pragma unroll
    for (int i = 0; i < 16; ++i) {
        if (!((i >> JB) & 1)) {
            const int i1 = i | (1 << JB);
            float a0 = p[i], a1 = p[i1];
            p[i]  = c * a0 - s * a1;
            p[i1] = s * a0 + c * a1;
        }
    }
}

// RY across lane bit 0/1 via DPP quad_perm (VALU pipe, verified r9/r10).
// CTRL: 0xB1 = xor lane^1, 0x4E = xor lane^2.  sg = (lane bit set)? +s : -s
template <int CTRL>
__device__ __forceinline__ void ry_dpp(float (&p)[16], float c, float sg) {
#pragma unroll
    for (int i = 0; i < 16; ++i) {
        float partner = __int_as_float(__builtin_amdgcn_update_dpp(
            0, __float_as_int(p[i]), CTRL, 0xF, 0xF, true));
        p[i] = c * p[i] + sg * partner;
    }
}

__global__ __launch_bounds__(NT, 4)
void vqc_kernel(const float* __restrict__ X,    // (512,14)
                const float* __restrict__ TH,   // (6,14)
                const float* __restrict__ A,    // (14,28)
                const float* __restrict__ Bc,   // (14,28)  unused: state stays real
                const float* __restrict__ D,    // (14,8)
                float* __restrict__ out)        // (512,2)
{
    __shared__ __align__(16) float st[NSTATE];  // 64 KiB real state
    __shared__ float2 tb[DEPTH * NQ];           // (cos,sin) per theta
    __shared__ float2 xf[NQ];                   // (c-s, c+s) per amplitude bit j
    __shared__ float  red[2 * (NT / 64)];

    const int t = threadIdx.x;
    const int b = blockIdx.x;

    // ---- trig tables (uniform work once per block) ----
    if (t < DEPTH * NQ) {
        float s, c;
        __sincosf(0.5f * TH[t], &s, &c);
        tb[t] = make_float2(c, s);
    } else if (t < DEPTH * NQ + NQ) {
        const int j = t - DEPTH * NQ;           // amplitude-bit j <-> wire 13-j
        float s, c;
        __sincosf(0.5f * X[b * NQ + (13 - j)], &s, &c);
        xf[j] = make_float2(c - s, c + s);
    }
    __syncthreads();

    // ---- layer 0 P1: product state at sigma(n), rotate wires 13..10 (amp 0-3) ----
    {
        const int mt = sigma(t << 4);
        float sh = 1.0f / 128.0f;
#pragma unroll
        for (int j = 4; j < 14; ++j) {
            float2 f = xf[j];
            sh *= ((mt >> j) & 1) ? f.y : f.x;
        }
        float fa[4], fb[4];
#pragma unroll
        for (int j = 0; j < 4; ++j) {
            float2 f = xf[j];
            const int mj = (mt >> j) & 1;
            fa[j] = mj ? f.y : f.x;
            fb[j] = mj ? f.x : f.y;
        }
        float p[16];
#pragma unroll
        for (int i = 0; i < 16; ++i) {
            const int sl = sigma(i);
            float v = sh;
            v *= (sl & 1)        ? fb[0] : fa[0];
            v *= ((sl >> 1) & 1) ? fb[1] : fa[1];
            v *= ((sl >> 2) & 1) ? fb[2] : fa[2];
            v *= ((sl >> 3) & 1) ? fb[3] : fa[3];
            p[i] = v;
        }
        float2 q0 = tb[13], q1 = tb[12], q2 = tb[11], q3 = tb[10];
        ry16<0>(p, q0.x, q0.y);
        ry16<1>(p, q1.x, q1.y);
        ry16<2>(p, q2.x, q2.y);
        ry16<3>(p, q3.x, q3.y);
        const int wb = swz(t << 4);
#pragma unroll
        for (int g = 0; g < 4; ++g)
            *(float4*)&st[wb ^ (g << 2)] =
                make_float4(p[4 * g], p[4 * g + 1], p[4 * g + 2], p[4 * g + 3]);
    }
    __syncthreads();

    // ---- layers: P1 (CNOT + 13-10), P2 (9-6 reg + 5,4 DPP), P3 (3-0) ----
    for (int k = 0; k < DEPTH; ++k) {
        const float2* tbk = tb + k * NQ;

        if (k > 0) {
            // P1: gather through sigma (b128). The lane-dependent XOR 12
            // (t0 = n bit 4) flips only float4-group bits -> folded into the
            // read address; remaining permute is compile-time reg renaming.
            const int rb = swz(sigma(t << 4) & ~15) ^ ((t & 1) * 12);
            float tmpf[16];
#pragma unroll
            for (int g = 0; g < 4; ++g)
                *(float4*)&tmpf[g * 4] = *(const float4*)&st[rb ^ (g << 2)];
            float p[16];
#pragma unroll
            for (int i = 0; i < 16; ++i) {
                const int i0 = i & 1, i1 = (i >> 1) & 1, i2 = (i >> 2) & 1, i3 = (i >> 3) & 1;
                const int s = (i0 ^ i1 ^ i2) | ((i1 ^ i2) << 1) | ((i2 ^ i3) << 2) | (i3 << 3);
                p[i] = tmpf[s];                  // compile-time shuffle
            }
            __syncthreads();                     // all gather-reads before any write
            float2 q0 = tbk[13], q1 = tbk[12], q2 = tbk[11], q3 = tbk[10];
            ry16<0>(p, q0.x, q0.y);
            ry16<1>(p, q1.x, q1.y);
            ry16<2>(p, q2.x, q2.y);
            ry16<3>(p, q3.x, q3.y);
            const int wb = swz(t << 4);
#pragma unroll
            for (int g = 0; g < 4; ++g)
                *(float4*)&st[wb ^ (g << 2)] =
                    make_float4(p[4 * g], p[4 * g + 1], p[4 * g + 2], p[4 * g + 3]);
            __syncthreads();
        }

        // P2: in-place RMW. regs = amp 4-7 (wires 9-6); DPP lanes t0,t1 = amp 8,9
        // (wires 5,4). Pairs over amp bit 5 -> additive +32 dwords (ds_read2).
        {
            const int raw = ((t >> 2) & 15) | ((t & 1) << 8) | ((t & 2) << 8)
                          | (((t >> 6) & 15) << 10);
            const int base2 = swz(raw);
            float p[16];
#pragma unroll
            for (int ip = 0; ip < 16; ++ip) {
                if ((ip & 2) == 0) {
                    const int v = base2 ^ (ip << 4) ^ (ip & 12);   // swz(ip<<4) folded
                    p[ip]     = st[v];
                    p[ip | 2] = st[v + 32];
                }
            }
            float2 q0 = tbk[9], q1 = tbk[8], q2 = tbk[7], q3 = tbk[6];
            ry16<0>(p, q0.x, q0.y);             // amp4 <-> wire 9
            ry16<1>(p, q1.x, q1.y);             // amp5 <-> wire 8
            ry16<2>(p, q2.x, q2.y);             // amp6 <-> wire 7
            ry16<3>(p, q3.x, q3.y);             // amp7 <-> wire 6
            float2 w5 = tbk[5], w4 = tbk[4];
            const float sg5 = (t & 1) ? w5.y : -w5.y;   // amp8 = lane bit 0
            const float sg4 = (t & 2) ? w4.y : -w4.y;   // amp9 = lane bit 1
            ry_dpp<0xB1>(p, w5.x, sg5);
            ry_dpp<0x4E>(p, w4.x, sg4);
#pragma unroll
            for (int ip = 0; ip < 16; ++ip) {
                if ((ip & 2) == 0) {
                    const int v = base2 ^ (ip << 4) ^ (ip & 12);
                    st[v]      = p[ip];
                    st[v + 32] = p[ip | 2];
                }
            }
            __syncthreads();
        }

        // P3: in-place RMW. regs = amp 10-13 (wires 3-0). Addresses purely
        // additive: base + i*1024 dwords (swz untouched) -> read2st64 / imm offsets.
        {
            const int base3 = swz(t);
            float p[16];
#pragma unroll
            for (int i = 0; i < 16; ++i) p[i] = st[base3 + (i << 10)];
            float2 q0 = tbk[3], q1 = tbk[2], q2 = tbk[1], q3 = tbk[0];
            ry16<0>(p, q0.x, q0.y);             // amp10 <-> wire 3
            ry16<1>(p, q1.x, q1.y);             // amp11 <-> wire 2
            ry16<2>(p, q2.x, q2.y);             // amp12 <-> wire 1
            ry16<3>(p, q3.x, q3.y);             // amp13 <-> wire 0
#pragma unroll
            for (int i = 0; i < 16; ++i) st[base3 + (i << 10)] = p[i];
            __syncthreads();
        }
    }

    // ---- expectations (real state: B drops out) ----
    float e[2];
#pragma unroll
    for (int q = 0; q < 2; ++q) {
        const int shift = 11 - q;
        float dg[8];
#pragma unroll
        for (int i = 0; i < 7; ++i) dg[i] = 2.0f * D[q * 8 + i + 1];
        dg[7] = 0.0f;
        float acc = 0.0f;
        const int lowmask = (1 << shift) - 1;
        for (int r = t; r < NSTATE / 8; r += NT) {   // 2 iterations
            const int base = ((r >> shift) << (shift + 3)) | (r & lowmask);
            float ps[8];
#pragma unroll
            for (int i = 0; i < 8; ++i) ps[i] = st[swz(base + (i << shift))];
#pragma unroll
            for (int i = 0; i < 8; ++i) acc += dg[i] * ps[i] * ps[i];
            int kk = 0;
#pragma unroll
            for (int i = 1; i < 8; ++i)
#pragma unroll
                for (int j = 0; j < i; ++j, ++kk)
                    acc += 2.0f * A[q * 28 + kk] * ps[i] * ps[j];
        }
        e[q] = acc;
    }

    // ---- block reduction ----
    float v0 = e[0], v1 = e[1];
#pragma unroll
    for (int o = 32; o > 0; o >>= 1) {
        v0 += __shfl_down(v0, o);
        v1 += __shfl_down(v1, o);
    }
    if ((t & 63) == 0) {
        red[(t >> 6) * 2]     = v0;
        red[(t >> 6) * 2 + 1] = v1;
    }
    __syncthreads();
    if (t == 0) {
        float s0 = 0.0f, s1 = 0.0f;
#pragma unroll
        for (int i = 0; i < NT / 64; ++i) { s0 += red[i * 2]; s1 += red[i * 2 + 1]; }
        out[b * 2 + 0] = s0;
        out[b * 2 + 1] = s1;
    }
}

extern "C" void kernel_launch(void* const* d_in, const int* in_sizes, int n_in,
                              void* d_out, int out_size, void* d_ws, size_t ws_size,
                              hipStream_t stream) {
    const float* X  = (const float*)d_in[0];
    const float* TH = (const float*)d_in[1];
    const float* A  = (const float*)d_in[2];
    const float* Bc = (const float*)d_in[3];
    const float* D  = (const float*)d_in[4];
    float* out = (float*)d_out;
    vqc_kernel<<<512, NT, 0, stream>>>(X, TH, A, Bc, D, out);
}